// Round 6
// baseline (74103.839 us; speedup 1.0000x reference)
//
#include <hip/hip_runtime.h>

#define S_LEN 131072
#define NIN   100
#define NH    40
#define TANH_SCALE 2.8853900817779268f   // 2*log2(e), folded into Wh/xproj

// ---------------------------------------------------------------------------
// permlane swap wrappers (r4 bench: LDS_Block_Size==0 proves this path compiles)
// ---------------------------------------------------------------------------
#if defined(__has_builtin)
#if __has_builtin(__builtin_amdgcn_permlane32_swap) && __has_builtin(__builtin_amdgcn_permlane16_swap)
#define HAS_PLSWAP 1
#endif
#endif
#ifndef HAS_PLSWAP
#define HAS_PLSWAP 0
#endif

#if HAS_PLSWAP
typedef unsigned int v2u __attribute__((ext_vector_type(2)));

__device__ __forceinline__ void plswap32(float& a, float& b) {
    v2u r = __builtin_amdgcn_permlane32_swap((unsigned)__float_as_int(a),
                                             (unsigned)__float_as_int(b), false, false);
    a = __int_as_float((int)r[0]);
    b = __int_as_float((int)r[1]);
}
__device__ __forceinline__ void plswap16(float& a, float& b) {
    v2u r = __builtin_amdgcn_permlane16_swap((unsigned)__float_as_int(a),
                                             (unsigned)__float_as_int(b), false, false);
    a = __int_as_float((int)r[0]);
    b = __int_as_float((int)r[1]);
}
#endif

__device__ __forceinline__ void replicate4(float H, volatile float* rl, int lane,
                                           float& v00, float& v01, float& v10, float& v11) {
#if HAS_PLSWAP
    (void)rl; (void)lane;
    float A = H, B = H;
    plswap32(A, B);
    v00 = A; v01 = A; plswap16(v00, v01);
    v10 = B; v11 = B; plswap16(v10, v11);
#else
    rl[lane] = H;
    int l15 = lane & 15;
    v00 = rl[l15];
    v01 = rl[16 + l15];
    v10 = rl[32 + l15];
    v11 = rl[48 + l15];
#endif
}

// ---------------------------------------------------------------------------
// phase 1: xsT[i][t] = (s[t]·Wx[i] + Wx_b[i] + Wh_b[i]) * TANH_SCALE
// ---------------------------------------------------------------------------
__global__ __launch_bounds__(256) void k_xproj(const float* __restrict__ s,
                                               const float* __restrict__ Wx,
                                               const float* __restrict__ Wxb,
                                               const float* __restrict__ Whb,
                                               float* __restrict__ xsT) {
    __shared__ float sm[64][NIN + 1];
    int tx = threadIdx.x, ty = threadIdx.y;
    int tid = ty * 64 + tx;
    size_t t0 = (size_t)blockIdx.x * 64;
    for (int e = tid; e < 64 * NIN; e += 256) {
        int r = e / NIN, c = e - r * NIN;
        sm[r][c] = s[(t0 + r) * NIN + c];
    }
    __syncthreads();
    size_t tcol = t0 + tx;
    for (int ig = 0; ig < 16; ++ig) {
        int i = ig * 4 + ty;
        float res = 0.0f;
        if (i < NH) {
            float acc = Wxb[i] + Whb[i];
            const float* wr = Wx + i * NIN;
#pragma unroll
            for (int k = 0; k < NIN; ++k) acc = fmaf(sm[tx][k], wr[k], acc);
            res = acc * TANH_SCALE;
        }
        xsT[(size_t)i * S_LEN + tcol] = res;
    }
}

// ---------------------------------------------------------------------------
// scan engine (shared by real scan and probe P1)
// ---------------------------------------------------------------------------
#define FMAC_ROR(ACC, RS, WS, K)                                                        \
    asm volatile("v_fmac_f32_dpp %0, %1, %2 row_ror:" #K " row_mask:0xf bank_mask:0xf"  \
                 : "+v"(ACC) : "v"(RS), "v"(WS))
#define FMAC_PLAIN(ACC, RS, WS)                                                         \
    asm volatile("v_fmac_f32 %0, %1, %2" : "+v"(ACC) : "v"(RS), "v"(WS))

template <int V, bool FAST>
__device__ __forceinline__ void step_core(float xp, float Hin, float& Hout,
                                          const float (&w)[3][16], bool sel,
                                          volatile float* rl, int lane) {
    float r00, r01, r10, r11;
    replicate4(Hin, rl, lane, r00, r01, r10, r11);
    float R0  = (V == 0) ? r00 : (V == 1) ? r01 : (V == 2) ? r10 : r11;
    float R1  = (V == 0) ? r01 : (V == 1) ? r00 : (V == 2) ? r11 : r10;
    float R2p = (V == 0) ? r10 : (V == 1) ? r11 : (V == 2) ? r00 : r01;
    float R2;
    if constexpr (FAST) {
        int roti = __builtin_amdgcn_update_dpp(0, __float_as_int(R2p), 0x128, 0xF, 0xF, false);
        R2 = sel ? __int_as_float(roti) : R2p;
    } else {
        R2 = R2p;
    }
    float a0 = xp, a1, a2;
    asm volatile("v_fmac_f32 %0, %1, %2" : "+v"(a0) : "v"(R0), "v"(w[0][0]));
    asm volatile("v_mul_f32 %0, %1, %2" : "=v"(a1) : "v"(R1), "v"(w[1][0]));
    asm volatile("v_mul_f32 %0, %1, %2" : "=v"(a2) : "v"(R2), "v"(w[2][0]));
#define KSTEP(K)                                                        \
    {                                                                   \
        FMAC_ROR(a2, R2, w[2][K], K);                                   \
        FMAC_ROR(a1, R1, w[1][K], K);                                   \
        if constexpr (!FAST || (K) <= 7) {} else {}                     \
        FMAC_ROR(a0, R0, w[0][K], K);                                   \
        if constexpr (!FAST || (K) <= 7) {} \
    }
#undef KSTEP
#define KSTEP(K)                                                        \
    {                                                                   \
        if constexpr (!FAST || (K) <= 7) { FMAC_ROR(a2, R2, w[2][K], K); } \
        FMAC_ROR(a1, R1, w[1][K], K);                                   \
        FMAC_ROR(a0, R0, w[0][K], K);                                   \
    }
    KSTEP(1) KSTEP(2) KSTEP(3) KSTEP(4) KSTEP(5) KSTEP(6) KSTEP(7)
    KSTEP(8) KSTEP(9) KSTEP(10) KSTEP(11) KSTEP(12) KSTEP(13) KSTEP(14) KSTEP(15)
#undef KSTEP
    float aa = (a1 + a2) + a0;
    float ex = __builtin_amdgcn_exp2f(aa);
    Hout = fmaf(-2.0f, __builtin_amdgcn_rcpf(ex + 1.0f), 1.0f);
}

template <int I>
__device__ __forceinline__ float& pick(float& a, float& b, float& c, float& d) {
    if constexpr (I == 0) return a;
    else if constexpr (I == 1) return b;
    else if constexpr (I == 2) return c;
    else return d;
}

// PROBE=true: 4 rotating H registers (dep distance 2 steps) -> recurrence broken,
// identical instruction stream -> measures pure throughput of the mix.
template <int V, bool FAST, bool PROBE>
__device__ void scan_loop(float H, const float (&w)[3][16], bool sel,
                          const float* __restrict__ xsT, float* __restrict__ hT,
                          int lane, float* __restrict__ out, volatile float* rl) {
    const float4* xr = (const float4*)(xsT + (size_t)lane * S_LEN);
    float4* hw4 = (float4*)(hT + (size_t)lane * S_LEN);
    float Hq0 = H, Hq1 = H * 0.5f + 0.01f, Hq2 = H * 0.25f - 0.01f, Hq3 = 0.02f - H;
    float4 cA = xr[0], cB = xr[1];
    float4 hb;
#define DOSTEP(I, XPV, SF)                                              \
    {                                                                   \
        float _hin = pick<PROBE ? ((I) & 3) : 0>(Hq0, Hq1, Hq2, Hq3);   \
        float& _hout = pick<PROBE ? (((I) + 2) & 3) : 0>(Hq0, Hq1, Hq2, Hq3); \
        step_core<V, FAST>(XPV, _hin, _hout, w, sel, rl, lane);         \
        SF = _hout;                                                     \
    }
    for (int t = 0; t < S_LEN; t += 16) {
        int q = t >> 2;
        float4 nA = xr[q + 2], nB = xr[q + 3];
        DOSTEP(0, cA.x, hb.x) DOSTEP(1, cA.y, hb.y) DOSTEP(2, cA.z, hb.z) DOSTEP(3, cA.w, hb.w)
        hw4[q] = hb;
        DOSTEP(4, cB.x, hb.x) DOSTEP(5, cB.y, hb.y) DOSTEP(6, cB.z, hb.z) DOSTEP(7, cB.w, hb.w)
        hw4[q + 1] = hb;
        cA = xr[q + 4];
        cB = xr[q + 5];
        DOSTEP(8, nA.x, hb.x) DOSTEP(9, nA.y, hb.y) DOSTEP(10, nA.z, hb.z) DOSTEP(11, nA.w, hb.w)
        hw4[q + 2] = hb;
        DOSTEP(12, nB.x, hb.x) DOSTEP(13, nB.y, hb.y) DOSTEP(14, nB.z, hb.z) DOSTEP(15, nB.w, hb.w)
        hw4[q + 3] = hb;
    }
#undef DOSTEP
    if constexpr (PROBE) {
        hT[lane] = Hq0 + Hq1 + Hq2 + Hq3;   // sink (hT fully overwritten by real scan)
    } else {
        if (lane < NH) out[lane] = Hq0;     // h_final
    }
}

// measured preamble: slot->group mapping + FAST probe + skewed weights
__device__ __forceinline__ void scan_preamble(const float* __restrict__ Whw, int lane,
                                              volatile float* rl, float (&w)[3][16],
                                              int& g0, bool& selrot, bool& okfast) {
    float v00, v01, v10, v11;
    replicate4(__int_as_float(lane), rl, lane, v00, v01, v10, v11);
    int J0 = __float_as_int(v00), J1 = __float_as_int(v01);
    int J2 = __float_as_int(v10), J3 = __float_as_int(v11);
    g0 = __builtin_amdgcn_readfirstlane(J0) >> 4;
    int g1 = __builtin_amdgcn_readfirstlane(J1) >> 4;
    int g2 = __builtin_amdgcn_readfirstlane(J2) >> 4;
    int g3 = __builtin_amdgcn_readfirstlane(J3) >> 4;

    int Jg2 = (g0 == 2) ? J0 : (g1 == 2) ? J1 : (g2 == 2) ? J2 : J3;
    int rot2 = __builtin_amdgcn_update_dpp(0, Jg2, 0x128, 0xF, 0xF, false);
    int needed = 32 + (lane & 7);
    selrot = (rot2 == needed);
    okfast = __all(selrot || (Jg2 == needed)) != 0;

#pragma unroll
    for (int c = 0; c < 3; ++c) {
        int Jc = (g0 == c) ? J0 : (g1 == c) ? J1 : (g2 == c) ? J2 : J3;
        int base = (c == 2 && okfast) ? needed : Jc;
        {
            int col = base;
            w[c][0] = (lane < NH && col < NH) ? Whw[lane * NH + col] * TANH_SCALE : 0.0f;
        }
#define WK(K)                                                                       \
    {                                                                               \
        int col = __builtin_amdgcn_update_dpp(0, base, 0x120 + K, 0xF, 0xF, false); \
        w[c][K] = (lane < NH && col < NH) ? Whw[lane * NH + col] * TANH_SCALE : 0.0f; \
    }
        WK(1) WK(2) WK(3) WK(4) WK(5) WK(6) WK(7) WK(8)
        WK(9) WK(10) WK(11) WK(12) WK(13) WK(14) WK(15)
#undef WK
    }
}

template <bool PROBE>
__device__ __forceinline__ void scan_dispatch(int g0, bool okfast, float H,
                                              const float (&w)[3][16], bool sel,
                                              const float* __restrict__ xsT,
                                              float* __restrict__ hT, int lane,
                                              float* __restrict__ out, volatile float* rl) {
    if (okfast) {
        switch (g0) {
            case 0:  scan_loop<0, true, PROBE>(H, w, sel, xsT, hT, lane, out, rl); break;
            case 1:  scan_loop<1, true, PROBE>(H, w, sel, xsT, hT, lane, out, rl); break;
            case 2:  scan_loop<2, true, PROBE>(H, w, sel, xsT, hT, lane, out, rl); break;
            default: scan_loop<3, true, PROBE>(H, w, sel, xsT, hT, lane, out, rl); break;
        }
    } else {
        switch (g0) {
            case 0:  scan_loop<0, false, PROBE>(H, w, sel, xsT, hT, lane, out, rl); break;
            case 1:  scan_loop<1, false, PROBE>(H, w, sel, xsT, hT, lane, out, rl); break;
            case 2:  scan_loop<2, false, PROBE>(H, w, sel, xsT, hT, lane, out, rl); break;
            default: scan_loop<3, false, PROBE>(H, w, sel, xsT, hT, lane, out, rl); break;
        }
    }
}

// ---------------------------------------------------------------------------
// phase 2: real scan (unchanged engine, known-correct, r4 config: grid=1)
// ---------------------------------------------------------------------------
__global__ __launch_bounds__(64) void k_scan(const float* __restrict__ xsT,
                                             float* __restrict__ hT,
                                             const float* __restrict__ Whw,
                                             const float* __restrict__ h0,
                                             float* __restrict__ out) {
    __shared__ float rl[64];
    int lane = threadIdx.x;
    float w[3][16];
    int g0; bool selrot, okfast;
    scan_preamble(Whw, lane, rl, w, g0, selrot, okfast);
    float H = (lane < NH) ? h0[lane] : 0.0f;
    scan_dispatch<false>(g0, okfast, H, w, selrot, xsT, hT, lane, out, rl);
}

// PROBE 1: exact step stream, recurrence broken (4 rotating H regs).
__global__ __launch_bounds__(64) void k_p1(const float* __restrict__ xsT,
                                           float* __restrict__ hT,
                                           const float* __restrict__ Whw,
                                           const float* __restrict__ h0) {
    __shared__ float rl[64];
    int lane = threadIdx.x;
    float w[3][16];
    int g0; bool selrot, okfast;
    scan_preamble(Whw, lane, rl, w, g0, selrot, okfast);
    float H = (lane < NH) ? h0[lane] : 0.0f;
    scan_dispatch<true>(g0, okfast, H, w, selrot, xsT, hT, lane, hT, rl);
}

// PROBE 2: 48 DPP fmacs/iter, 3 independent interleaved chains.
__global__ __launch_bounds__(64) void k_p2(const float* __restrict__ h0,
                                           float* __restrict__ sink) {
    int lane = threadIdx.x;
    float base = h0[lane % NH] * 0.125f + 0.5f;
    float R0 = base, R1 = base * 1.125f, R2 = base * 0.875f;
    float w0 = 1.0e-6f, w1 = 1.1e-6f, w2 = 0.9e-6f;
    float a0 = 0.f, a1 = 0.f, a2 = 0.f;
    for (int t = 0; t < S_LEN; ++t) {
#define PK(K) FMAC_ROR(a2, R2, w2, K); FMAC_ROR(a1, R1, w1, K); FMAC_ROR(a0, R0, w0, K);
        PK(1) PK(2) PK(3) PK(4) PK(5) PK(6) PK(7) PK(8)
        PK(9) PK(10) PK(11) PK(12) PK(13) PK(14) PK(15) PK(1)
#undef PK
    }
    sink[lane] = a0 + a1 + a2;
}

// PROBE 3: 48 plain fmacs/iter, same interleave — baseline single-wave cadence.
__global__ __launch_bounds__(64) void k_p3(const float* __restrict__ h0,
                                           float* __restrict__ sink) {
    int lane = threadIdx.x;
    float base = h0[lane % NH] * 0.125f + 0.5f;
    float R0 = base, R1 = base * 1.125f, R2 = base * 0.875f;
    float w0 = 1.0e-6f, w1 = 1.1e-6f, w2 = 0.9e-6f;
    float a0 = 0.f, a1 = 0.f, a2 = 0.f;
    for (int t = 0; t < S_LEN; ++t) {
#define PP(K) FMAC_PLAIN(a2, R2, w2); FMAC_PLAIN(a1, R1, w1); FMAC_PLAIN(a0, R0, w0);
        PP(1) PP(2) PP(3) PP(4) PP(5) PP(6) PP(7) PP(8)
        PP(9) PP(10) PP(11) PP(12) PP(13) PP(14) PP(15) PP(1)
#undef PP
    }
    sink[lane] = a0 + a1 + a2;
}

// ---------------------------------------------------------------------------
// phase 3: per-step softmax
// ---------------------------------------------------------------------------
__global__ __launch_bounds__(256) void k_out(const float* __restrict__ hT,
                                             const float* __restrict__ Wy,
                                             const float* __restrict__ Wyb,
                                             float* __restrict__ out) {
    int lane = threadIdx.x & 63;
    int wv = threadIdx.x >> 6;
    int t = __builtin_amdgcn_readfirstlane(blockIdx.x * 4 + wv);
    const float* hp = hT + t;
    float hv[NH];
#pragma unroll
    for (int j = 0; j < NH; ++j) hv[j] = hp[(size_t)j * S_LEN];
    int v = lane;
    const float* wr0 = Wy + v * NH;
    float z0 = Wyb[v];
#pragma unroll
    for (int j = 0; j < NH; ++j) z0 = fmaf(hv[j], wr0[j], z0);
    bool has2 = (v < NIN - 64);
    int v2 = v + 64;
    float z1 = -1e30f;
    if (has2) {
        const float* wr1 = Wy + v2 * NH;
        float acc = Wyb[v2];
#pragma unroll
        for (int j = 0; j < NH; ++j) acc = fmaf(hv[j], wr1[j], acc);
        z1 = acc;
    }
    float mx = fmaxf(z0, z1);
#pragma unroll
    for (int o = 32; o; o >>= 1) mx = fmaxf(mx, __shfl_xor(mx, o, 64));
    const float LOG2E = 1.4426950408889634f;
    float e0 = __builtin_amdgcn_exp2f((z0 - mx) * LOG2E);
    float e1 = 0.0f;
    if (has2) e1 = __builtin_amdgcn_exp2f((z1 - mx) * LOG2E);
    float sum = e0 + e1;
#pragma unroll
    for (int o = 32; o; o >>= 1) sum += __shfl_xor(sum, o, 64);
    float r = __builtin_amdgcn_rcpf(sum);
    r = r * (2.0f - sum * r);
    float* yrow = out + NH + (size_t)t * NIN;
    yrow[v] = e0 * r;
    if (has2) yrow[v2] = e1 * r;
}

// ---------------------------------------------------------------------------
extern "C" void kernel_launch(void* const* d_in, const int* in_sizes, int n_in,
                              void* d_out, int out_size, void* d_ws, size_t ws_size,
                              hipStream_t stream) {
    const float* s   = (const float*)d_in[0];
    const float* h0  = (const float*)d_in[1];
    const float* Wxw = (const float*)d_in[2];
    const float* Wxb = (const float*)d_in[3];
    const float* Whw = (const float*)d_in[4];
    const float* Whb = (const float*)d_in[5];
    const float* Wyw = (const float*)d_in[6];
    const float* Wyb = (const float*)d_in[7];
    float* out = (float*)d_out;

    float* xsT = out + NH;            // inside ys region, overwritten by k_out later
    float* hT  = (float*)d_ws;        // 33.55 MB scratch

    k_xproj<<<dim3(S_LEN / 64), dim3(64, 4), 0, stream>>>(s, Wxw, Wxb, Whb, xsT);
    // --- diagnostic probes (results discarded; hT fully overwritten by k_scan) ---
    k_p1<<<1, 64, 0, stream>>>(xsT, hT, Whw, h0);
    k_p2<<<1, 64, 0, stream>>>(h0, hT);
    k_p3<<<1, 64, 0, stream>>>(h0, hT);
    // --- real computation (unchanged, known-correct) ---
    k_scan<<<1, 64, 0, stream>>>(xsT, hT, Whw, h0, out);
    k_out<<<S_LEN / 4, 256, 0, stream>>>(hT, Wyw, Wyb, out);
}